// Round 9
// baseline (208.117 us; speedup 1.0000x reference)
//
#include <hip/hip_runtime.h>
#include <hip/hip_bf16.h>

typedef __bf16 bf16_t;
typedef __bf16 bf16x8 __attribute__((ext_vector_type(8)));
typedef float f32x4 __attribute__((ext_vector_type(4)));
typedef float f32x16 __attribute__((ext_vector_type(16)));
typedef unsigned uint2v __attribute__((ext_vector_type(2)));

#define NV 8000   // D*H*W
#define QB 125    // NV / 64

__device__ __forceinline__ bf16x8 cvt_bf16x8(const float* __restrict__ p) {
    float4 a = *reinterpret_cast<const float4*>(p);
    float4 b = *reinterpret_cast<const float4*>(p + 4);
    bf16x8 r;
    r[0] = (bf16_t)a.x; r[1] = (bf16_t)a.y; r[2] = (bf16_t)a.z; r[3] = (bf16_t)a.w;
    r[4] = (bf16_t)b.x; r[5] = (bf16_t)b.y; r[6] = (bf16_t)b.z; r[7] = (bf16_t)b.w;
    return r;
}

__device__ __forceinline__ unsigned pack2(float a, float b) {
    union { bf16_t h[2]; unsigned u; } x;
    x.h[0] = (bf16_t)a; x.h[1] = (bf16_t)b;
    return x.u;
}

// sigma permutation: n = 125c + a  ->  sigma = 64a + c (projection gather
// becomes contiguous).
__device__ __forceinline__ int sigma_of(int n) {
    int c = n / 125, a = n - 125 * c;
    return a * 64 + c;
}

// ---------------------------------------------------------------------------
// Kernel 1: fused QKV convs, 16-voxel tiles (grid 2*500).  (unchanged, R5)
// ---------------------------------------------------------------------------
__global__ __launch_bounds__(256) void qkv_kernel(
    const float* __restrict__ x,
    const float* __restrict__ wq, const float* __restrict__ bq,
    const float* __restrict__ wk, const float* __restrict__ bk,
    const float* __restrict__ wv, const float* __restrict__ bv,
    bf16_t* __restrict__ Q, bf16_t* __restrict__ Kr, bf16_t* __restrict__ Vt)
{
    __shared__ __align__(16) char xb[16 * 128];

    const int tid = threadIdx.x;
    const int b  = blockIdx.x / 500;
    const int n0 = (blockIdx.x % 500) * 16;

    {
        int c = tid >> 2, seg = tid & 3;
        float4 v4 = *reinterpret_cast<const float4*>(&x[((size_t)b * 64 + c) * NV + n0 + seg * 4]);
        #pragma unroll
        for (int j = 0; j < 4; ++j) {
            int vx = seg * 4 + j;
            *reinterpret_cast<bf16_t*>(xb + vx * 128 + ((c * 2) ^ ((vx & 7) << 4))) =
                (bf16_t)((&v4.x)[j]);
        }
    }
    __syncthreads();

    const int w  = tid >> 6;
    const int lane = tid & 63;
    const int g  = lane >> 4;
    const int lr = lane & 15;

    const bf16x8 xa0 = *reinterpret_cast<const bf16x8*>(
        xb + lr * 128 + ((16 * g) ^ ((lr & 7) << 4)));
    const bf16x8 xa1 = *reinterpret_cast<const bf16x8*>(
        xb + lr * 128 + ((64 + 16 * g) ^ ((lr & 7) << 4)));

    const f32x4 zero4 = {0.f, 0.f, 0.f, 0.f};
    const float QSCALE = 0.125f * 1.44269504088896f;
    const int kout = w * 16 + lr;

    {   // Q (sigma-ordered)
        bf16x8 wb0 = cvt_bf16x8(wq + kout * 64 + 8 * g);
        bf16x8 wb1 = cvt_bf16x8(wq + kout * 64 + 32 + 8 * g);
        f32x4 acc = __builtin_amdgcn_mfma_f32_16x16x32_bf16(xa0, wb0, zero4, 0, 0, 0);
        acc = __builtin_amdgcn_mfma_f32_16x16x32_bf16(xa1, wb1, acc, 0, 0, 0);
        const float bias = bq[kout];
        #pragma unroll
        for (int j = 0; j < 4; ++j) {
            const int sig = sigma_of(n0 + 4 * g + j);
            Q[((size_t)b * NV + sig) * 64 + kout] = (bf16_t)((acc[j] + bias) * QSCALE);
        }
    }
    {   // K (n-ordered)
        bf16x8 wb0 = cvt_bf16x8(wk + kout * 64 + 8 * g);
        bf16x8 wb1 = cvt_bf16x8(wk + kout * 64 + 32 + 8 * g);
        f32x4 acc = __builtin_amdgcn_mfma_f32_16x16x32_bf16(xa0, wb0, zero4, 0, 0, 0);
        acc = __builtin_amdgcn_mfma_f32_16x16x32_bf16(xa1, wb1, acc, 0, 0, 0);
        const float bias = bk[kout];
        #pragma unroll
        for (int j = 0; j < 4; ++j)
            Kr[((size_t)b * NV + n0 + 4 * g + j) * 64 + kout] = (bf16_t)(acc[j] + bias);
    }
    {   // V (n-ordered, packed)
        bf16x8 wb0 = cvt_bf16x8(wv + kout * 64 + 8 * g);
        bf16x8 wb1 = cvt_bf16x8(wv + kout * 64 + 32 + 8 * g);
        f32x4 acc = __builtin_amdgcn_mfma_f32_16x16x32_bf16(xa0, wb0, zero4, 0, 0, 0);
        acc = __builtin_amdgcn_mfma_f32_16x16x32_bf16(xa1, wb1, acc, 0, 0, 0);
        const float bias = bv[kout];
        union { uint2 u2; bf16_t h[4]; } pk;
        #pragma unroll
        for (int j = 0; j < 4; ++j) pk.h[j] = (bf16_t)(acc[j] + bias);
        *reinterpret_cast<uint2*>(&Vt[((size_t)b * 64 + kout) * NV + n0 + 4 * g]) = pk.u2;
    }
}

// ---------------------------------------------------------------------------
// Kernel 2: flash attention, barrier-free 1-wave blocks.
// Each wave: 32 queries, loops its split's K-tiles; K/V fragments loaded
// global->register directly (per-lane addr == R8's fragment-linear slot).
// Cross-tile pipeline: QK(t+1) overlaps SM(t); K(t+2)/V(t+1) loads issued
// as their registers die.  P redistributed in-register via permlane32_swap.
// Defer-max THR=8 (exp2 domain).  Writes unnormalized bf16 partial O + (m,l).
// ---------------------------------------------------------------------------
template<int S>
__global__ __launch_bounds__(64) void attn_kernel(
    const bf16_t* __restrict__ Q, const bf16_t* __restrict__ Kr,
    const bf16_t* __restrict__ Vt, bf16_t* __restrict__ Op, float* __restrict__ ml)
{
    const int bid  = blockIdx.x;
    const int grp  = bid % (2 * S);          // consecutive bids spread XCDs
    const int s    = grp >> 1;
    const int b    = grp & 1;
    const int j    = bid / (2 * S);          // 0..251
    const int qb   = j >> 2;
    const int w    = j & 3;
    const int q0   = qb * 128;
    const int t0   = (125 * s) / S;
    const int t1   = (125 * (s + 1)) / S;
    const int lane = threadIdx.x & 63;
    const int lo   = lane & 31;
    const int hi   = lane >> 5;

    const int q  = q0 + w * 32 + lo;
    const int qc = q < NV ? q : NV - 1;

    bf16x8 bqf[4];
    {
        const bf16_t* qrow = Q + ((size_t)b * NV + qc) * 64 + hi * 8;
        #pragma unroll
        for (int kk = 0; kk < 4; ++kk)
            bqf[kk] = *reinterpret_cast<const bf16x8*>(qrow + kk * 16);
    }

    // per-lane streaming pointers (advance as tiles are issued)
    const char* kp = (const char*)(Kr + (size_t)b * NV * 64);
    const char* vp = (const char*)(Vt + (size_t)b * 64 * NV);
    const char* kptr  = kp + (size_t)t0 * 8192 + lo * 128 + hi * 16;
    const char* vptr0 = vp + (size_t)lo * (NV * 2) + (size_t)t0 * 128 + hi * 16;
    const char* vptr1 = vptr0 + (size_t)32 * (NV * 2);

    bf16x8 kr[2][4];   // K(t) fragments: kr[kb][kk]
    bf16x8 vr[2][4];   // V(t) fragments: vr[vb][ks]

#define ATTN_LOADK() do {                                                       \
    _Pragma("unroll")                                                           \
    for (int kb = 0; kb < 2; ++kb)                                              \
        _Pragma("unroll")                                                       \
        for (int kk = 0; kk < 4; ++kk)                                          \
            kr[kb][kk] = *reinterpret_cast<const bf16x8*>(kptr + kb * 4096 + kk * 32); \
    kptr += 8192; } while (0)

#define ATTN_LOADV() do {                                                       \
    _Pragma("unroll")                                                           \
    for (int ks = 0; ks < 4; ++ks) {                                            \
        vr[0][ks] = *reinterpret_cast<const bf16x8*>(vptr0 + ks * 32);          \
        vr[1][ks] = *reinterpret_cast<const bf16x8*>(vptr1 + ks * 32);          \
    }                                                                           \
    vptr0 += 128; vptr1 += 128; } while (0)

#define ATTN_QK(dst) do {                                                       \
    _Pragma("unroll")                                                           \
    for (int kb = 0; kb < 2; ++kb) {                                            \
        f32x16 acc_{};                                                          \
        _Pragma("unroll")                                                       \
        for (int kk = 0; kk < 4; ++kk)                                          \
            acc_ = __builtin_amdgcn_mfma_f32_32x32x16_bf16(kr[kb][kk], bqf[kk], acc_, 0, 0, 0); \
        dst[kb] = acc_; } } while (0)

    f32x16 acco[2]; acco[0] = f32x16{}; acco[1] = f32x16{};
    float m = -1e30f, l = 0.f;

    const int nt = t1 - t0;
    f32x16 sa[2], sa2[2];

    ATTN_LOADK();                 // K(t0)
    ATTN_LOADV();                 // V(t0)
    ATTN_QK(sa);                  // QK(t0)
    if (nt > 1) ATTN_LOADK();     // K(t0+1)

    for (int t = t0; t < t1; ++t) {
        if (t + 1 < t1) {
            ATTN_QK(sa2);                 // QK(t+1); kr dead after issue
            if (t + 2 < t1) ATTN_LOADK(); // K(t+2) -> full-iter latency window
        }

        // ---- softmax(t): 31-deep fmax tree + cross-half permlane ----
        float mx;
        {
            float v8[8];
            #pragma unroll
            for (int r = 0; r < 8; ++r)
                v8[r] = fmaxf(fmaxf(sa[0][r], sa[0][r + 8]),
                              fmaxf(sa[1][r], sa[1][r + 8]));
            float v4a = fmaxf(v8[0], v8[4]), v4b = fmaxf(v8[1], v8[5]);
            float v4c = fmaxf(v8[2], v8[6]), v4d = fmaxf(v8[3], v8[7]);
            mx = fmaxf(fmaxf(v4a, v4b), fmaxf(v4c, v4d));
        }
        {
            union { float f; unsigned u; } xu; xu.f = mx;
            uint2v r = __builtin_amdgcn_permlane32_swap(xu.u, xu.u, false, false);
            union { unsigned u; float f; } po; po.u = hi ? r[0] : r[1];
            mx = fmaxf(mx, po.f);
        }
        if (__any(mx > m + 8.0f)) {
            const float mn2 = fmaxf(m, mx);
            const float corr = exp2f(m - mn2);
            m = mn2;
            l *= corr;
            acco[0] *= corr;
            acco[1] *= corr;
        }

        float ps = 0.f;
        unsigned Uw[2][4][2];
        #pragma unroll
        for (int kb = 0; kb < 2; ++kb) {
            #pragma unroll
            for (int jj = 0; jj < 4; ++jj) {
                float p0 = exp2f(sa[kb][4 * jj + 0] - m);
                float p1 = exp2f(sa[kb][4 * jj + 1] - m);
                float p2 = exp2f(sa[kb][4 * jj + 2] - m);
                float p3 = exp2f(sa[kb][4 * jj + 3] - m);
                ps += (p0 + p1) + (p2 + p3);
                Uw[kb][jj][0] = pack2(p0, p1);
                Uw[kb][jj][1] = pack2(p2, p3);
            }
        }
        {
            union { float f; unsigned u; } xu; xu.f = ps;
            uint2v r = __builtin_amdgcn_permlane32_swap(xu.u, xu.u, false, false);
            union { unsigned u; float f; } po; po.u = hi ? r[0] : r[1];
            ps += po.f;
        }
        l += ps;

        // ---- PV(t): P fragments via permlane32_swap; V from registers ----
        #pragma unroll
        for (int kb = 0; kb < 2; ++kb) {
            #pragma unroll
            for (int e = 0; e < 2; ++e) {
                uint2v r0 = __builtin_amdgcn_permlane32_swap(
                    Uw[kb][2 * e][0], Uw[kb][2 * e + 1][0], false, false);
                uint2v r1 = __builtin_amdgcn_permlane32_swap(
                    Uw[kb][2 * e][1], Uw[kb][2 * e + 1][1], false, false);
                union { unsigned u[4]; bf16x8 v; } pf;
                pf.u[0] = r0[0]; pf.u[1] = r1[0];
                pf.u[2] = r0[1]; pf.u[3] = r1[1];
                const int ks = kb * 2 + e;
                #pragma unroll
                for (int vb = 0; vb < 2; ++vb)
                    acco[vb] = __builtin_amdgcn_mfma_f32_32x32x16_bf16(
                        vr[vb][ks], pf.v, acco[vb], 0, 0, 0);
            }
        }

        if (t + 1 < t1) {
            ATTN_LOADV();                 // V(t+1); vr dead after PV issue
            sa[0] = sa2[0]; sa[1] = sa2[1];
        }
    }

    // epilogue: lane owns query q; acco[vb][4j+i] = O[q][32vb + 8j + 4hi + i]
    if (q < NV) {
        const size_t obase = ((size_t)(s * 2 + b) * NV + q) * 64;
        #pragma unroll
        for (int vb = 0; vb < 2; ++vb) {
            #pragma unroll
            for (int jj = 0; jj < 4; ++jj) {
                union { uint2 u2; bf16_t h[4]; } pk;
                #pragma unroll
                for (int i = 0; i < 4; ++i) pk.h[i] = (bf16_t)acco[vb][4 * jj + i];
                *reinterpret_cast<uint2*>(&Op[obase + vb * 32 + 8 * jj + 4 * hi]) = pk.u2;
            }
        }
        if (hi == 0) {
            float2 t2; t2.x = m; t2.y = l;
            *reinterpret_cast<float2*>(&ml[((size_t)(s * 2 + b) * NV + q) * 2]) = t2;
        }
    }
#undef ATTN_LOADK
#undef ATTN_LOADV
#undef ATTN_QK
}

// ---------------------------------------------------------------------------
// Kernel 3: fused split-K combine + output projection, nf-split 4-way.
// (unchanged, R8; Op is bf16)
// ---------------------------------------------------------------------------
template<int S>
__global__ __launch_bounds__(256) void projc_kernel(
    const bf16_t* __restrict__ Op, const float* __restrict__ ml,
    const float* __restrict__ wo, const float* __restrict__ bo,
    float* __restrict__ out)
{
    __shared__ __align__(16) char bt[16 * 128];
    __shared__ float al[64 * 8];

    const int tid = threadIdx.x;
    const int b   = blockIdx.x / 500;
    const int rem = blockIdx.x % 500;
    const int a   = rem >> 2;
    const int nf  = rem & 3;

    if (tid < 64) {
        const int row = a * 64 + tid;
        float M = -1e30f;
        #pragma unroll
        for (int s = 0; s < S; ++s)
            M = fmaxf(M, ml[((size_t)(s * 2 + b) * NV + row) * 2]);
        float L = 0.f, av[S];
        #pragma unroll
        for (int s = 0; s < S; ++s) {
            const float mm = ml[((size_t)(s * 2 + b) * NV + row) * 2];
            const float ll = ml[((size_t)(s * 2 + b) * NV + row) * 2 + 1];
            const float aa = exp2f(mm - M);
            L += ll * aa;
            av[s] = aa;
        }
        const float inv = 1.0f / L;
        #pragma unroll
        for (int s = 0; s < S; ++s) al[tid * 8 + s] = av[s] * inv;
    }
    __syncthreads();

    {
        const int c = tid >> 2, sg = tid & 3;
        f32x4 acc = {0.f, 0.f, 0.f, 0.f};
        #pragma unroll
        for (int s = 0; s < S; ++s) {
            const float fac = al[c * 8 + s];
            union { uint2 u2; bf16_t h[4]; } cv;
            cv.u2 = *reinterpret_cast<const uint2*>(
                &Op[((size_t)(s * 2 + b) * NV + a * 64 + c) * 64 + nf * 16 + sg * 4]);
            #pragma unroll
            for (int jj = 0; jj < 4; ++jj) acc[jj] += fac * (float)cv.h[jj];
        }
        #pragma unroll
        for (int jj = 0; jj < 4; ++jj) {
            const int v = sg * 4 + jj;
            *reinterpret_cast<bf16_t*>(bt + v * 128 + ((c * 2) ^ ((v & 7) << 4))) =
                (bf16_t)acc[jj];
        }
    }
    __syncthreads();

    const int w  = tid >> 6;
    const int lane = tid & 63;
    const int g  = lane >> 4;
    const int lr = lane & 15;

    const int orow = w * 16 + lr;
    const bf16x8 wa0 = cvt_bf16x8(wo + orow * 64 + 8 * g);
    const bf16x8 wa1 = cvt_bf16x8(wo + orow * 64 + 32 + 8 * g);
    const float4 bo4 = *reinterpret_cast<const float4*>(&bo[w * 16 + 4 * g]);

    const f32x4 zero4 = {0.f, 0.f, 0.f, 0.f};
    const bf16x8 gb0 = *reinterpret_cast<const bf16x8*>(
        bt + lr * 128 + ((16 * g) ^ ((lr & 7) << 4)));
    const bf16x8 gb1 = *reinterpret_cast<const bf16x8*>(
        bt + lr * 128 + ((64 + 16 * g) ^ ((lr & 7) << 4)));
    f32x4 acc = __builtin_amdgcn_mfma_f32_16x16x32_bf16(wa0, gb0, zero4, 0, 0, 0);
    acc = __builtin_amdgcn_mfma_f32_16x16x32_bf16(wa1, gb1, acc, 0, 0, 0);
    #pragma unroll
    for (int jj = 0; jj < 4; ++jj) {
        const int o = w * 16 + 4 * g + jj;
        out[((size_t)b * 64 + o) * NV + a * 64 + nf * 16 + lr] = acc[jj] + (&bo4.x)[jj];
    }
}

// ---------------------------------------------------------------------------
extern "C" void kernel_launch(void* const* d_in, const int* in_sizes, int n_in,
                              void* d_out, int out_size, void* d_ws, size_t ws_size,
                              hipStream_t stream)
{
    const float* x  = (const float*)d_in[0];
    const float* wq = (const float*)d_in[1];
    const float* bq = (const float*)d_in[2];
    const float* wk = (const float*)d_in[3];
    const float* bk = (const float*)d_in[4];
    const float* wv = (const float*)d_in[5];
    const float* bv = (const float*)d_in[6];
    const float* wo = (const float*)d_in[7];
    const float* bo = (const float*)d_in[8];
    float* out = (float*)d_out;

    // ws: Q(2,048,000) | K(2,048,000) | Vt(2,048,000) | Op bf16 (S*2,048,000) | ml (S*128,000)
    char* ws = (char*)d_ws;
    bf16_t* Q  = (bf16_t*)(ws);
    bf16_t* Kr = (bf16_t*)(ws + 2048000);
    bf16_t* Vt = (bf16_t*)(ws + 4096000);

    int S = 4;
    if (ws_size < 6144000ull + 4ull * 2176000ull) S = 2;
    if (ws_size < 6144000ull + 2ull * 2176000ull) S = 1;

    bf16_t* Op = (bf16_t*)(ws + 6144000);
    float*  ml = (float*)(ws + 6144000 + (size_t)S * 2048000);

    qkv_kernel<<<dim3(2 * 500), dim3(256), 0, stream>>>(x, wq, bq, wk, bk, wv, bv, Q, Kr, Vt);

    if (S == 4) {
        attn_kernel<4><<<dim3(4 * 2 * 252), dim3(64), 0, stream>>>(Q, Kr, Vt, Op, ml);
        projc_kernel<4><<<dim3(2 * 500), dim3(256), 0, stream>>>(Op, ml, wo, bo, out);
    } else if (S == 2) {
        attn_kernel<2><<<dim3(2 * 2 * 252), dim3(64), 0, stream>>>(Q, Kr, Vt, Op, ml);
        projc_kernel<2><<<dim3(2 * 500), dim3(256), 0, stream>>>(Op, ml, wo, bo, out);
    } else {
        attn_kernel<1><<<dim3(1 * 2 * 252), dim3(64), 0, stream>>>(Q, Kr, Vt, Op, ml);
        projc_kernel<1><<<dim3(2 * 500), dim3(256), 0, stream>>>(Op, ml, wo, bo, out);
    }
}

// Round 10
// 159.509 us; speedup vs baseline: 1.3047x; 1.3047x over previous
//
#include <hip/hip_runtime.h>
#include <hip/hip_bf16.h>

typedef __bf16 bf16_t;
typedef __bf16 bf16x8 __attribute__((ext_vector_type(8)));
typedef float f32x4 __attribute__((ext_vector_type(4)));
typedef float f32x16 __attribute__((ext_vector_type(16)));
typedef unsigned uint2v __attribute__((ext_vector_type(2)));

#define NV 8000   // D*H*W
#define QB 125    // NV / 64

#if __has_builtin(__builtin_amdgcn_exp2f)
#define EXP2(x) __builtin_amdgcn_exp2f(x)
#else
#define EXP2(x) exp2f(x)
#endif

__device__ __forceinline__ bf16x8 cvt_bf16x8(const float* __restrict__ p) {
    float4 a = *reinterpret_cast<const float4*>(p);
    float4 b = *reinterpret_cast<const float4*>(p + 4);
    bf16x8 r;
    r[0] = (bf16_t)a.x; r[1] = (bf16_t)a.y; r[2] = (bf16_t)a.z; r[3] = (bf16_t)a.w;
    r[4] = (bf16_t)b.x; r[5] = (bf16_t)b.y; r[6] = (bf16_t)b.z; r[7] = (bf16_t)b.w;
    return r;
}

__device__ __forceinline__ unsigned pack2(float a, float b) {
    union { bf16_t h[2]; unsigned u; } x;
    x.h[0] = (bf16_t)a; x.h[1] = (bf16_t)b;
    return x.u;
}

// sigma permutation: n = 125c + a  ->  sigma = 64a + c (projection gather
// becomes contiguous).
__device__ __forceinline__ int sigma_of(int n) {
    int c = n / 125, a = n - 125 * c;
    return a * 64 + c;
}

// ---------------------------------------------------------------------------
// Kernel 1: fused QKV convs, 16-voxel tiles (grid 2*500).  (unchanged, R5)
// ---------------------------------------------------------------------------
__global__ __launch_bounds__(256) void qkv_kernel(
    const float* __restrict__ x,
    const float* __restrict__ wq, const float* __restrict__ bq,
    const float* __restrict__ wk, const float* __restrict__ bk,
    const float* __restrict__ wv, const float* __restrict__ bv,
    bf16_t* __restrict__ Q, bf16_t* __restrict__ Kr, bf16_t* __restrict__ Vt)
{
    __shared__ __align__(16) char xb[16 * 128];

    const int tid = threadIdx.x;
    const int b  = blockIdx.x / 500;
    const int n0 = (blockIdx.x % 500) * 16;

    {
        int c = tid >> 2, seg = tid & 3;
        float4 v4 = *reinterpret_cast<const float4*>(&x[((size_t)b * 64 + c) * NV + n0 + seg * 4]);
        #pragma unroll
        for (int j = 0; j < 4; ++j) {
            int vx = seg * 4 + j;
            *reinterpret_cast<bf16_t*>(xb + vx * 128 + ((c * 2) ^ ((vx & 7) << 4))) =
                (bf16_t)((&v4.x)[j]);
        }
    }
    __syncthreads();

    const int w  = tid >> 6;
    const int lane = tid & 63;
    const int g  = lane >> 4;
    const int lr = lane & 15;

    const bf16x8 xa0 = *reinterpret_cast<const bf16x8*>(
        xb + lr * 128 + ((16 * g) ^ ((lr & 7) << 4)));
    const bf16x8 xa1 = *reinterpret_cast<const bf16x8*>(
        xb + lr * 128 + ((64 + 16 * g) ^ ((lr & 7) << 4)));

    const f32x4 zero4 = {0.f, 0.f, 0.f, 0.f};
    const float QSCALE = 0.125f * 1.44269504088896f;
    const int kout = w * 16 + lr;

    {   // Q (sigma-ordered)
        bf16x8 wb0 = cvt_bf16x8(wq + kout * 64 + 8 * g);
        bf16x8 wb1 = cvt_bf16x8(wq + kout * 64 + 32 + 8 * g);
        f32x4 acc = __builtin_amdgcn_mfma_f32_16x16x32_bf16(xa0, wb0, zero4, 0, 0, 0);
        acc = __builtin_amdgcn_mfma_f32_16x16x32_bf16(xa1, wb1, acc, 0, 0, 0);
        const float bias = bq[kout];
        #pragma unroll
        for (int j = 0; j < 4; ++j) {
            const int sig = sigma_of(n0 + 4 * g + j);
            Q[((size_t)b * NV + sig) * 64 + kout] = (bf16_t)((acc[j] + bias) * QSCALE);
        }
    }
    {   // K (n-ordered)
        bf16x8 wb0 = cvt_bf16x8(wk + kout * 64 + 8 * g);
        bf16x8 wb1 = cvt_bf16x8(wk + kout * 64 + 32 + 8 * g);
        f32x4 acc = __builtin_amdgcn_mfma_f32_16x16x32_bf16(xa0, wb0, zero4, 0, 0, 0);
        acc = __builtin_amdgcn_mfma_f32_16x16x32_bf16(xa1, wb1, acc, 0, 0, 0);
        const float bias = bk[kout];
        #pragma unroll
        for (int j = 0; j < 4; ++j)
            Kr[((size_t)b * NV + n0 + 4 * g + j) * 64 + kout] = (bf16_t)(acc[j] + bias);
    }
    {   // V (n-ordered, packed)
        bf16x8 wb0 = cvt_bf16x8(wv + kout * 64 + 8 * g);
        bf16x8 wb1 = cvt_bf16x8(wv + kout * 64 + 32 + 8 * g);
        f32x4 acc = __builtin_amdgcn_mfma_f32_16x16x32_bf16(xa0, wb0, zero4, 0, 0, 0);
        acc = __builtin_amdgcn_mfma_f32_16x16x32_bf16(xa1, wb1, acc, 0, 0, 0);
        const float bias = bv[kout];
        union { uint2 u2; bf16_t h[4]; } pk;
        #pragma unroll
        for (int j = 0; j < 4; ++j) pk.h[j] = (bf16_t)(acc[j] + bias);
        *reinterpret_cast<uint2*>(&Vt[((size_t)b * 64 + kout) * NV + n0 + 4 * g]) = pk.u2;
    }
}

// ---------------------------------------------------------------------------
// Kernel 2: flash attention, 32x32x16, triple-buffered LDS, ONE barrier/tile:
//   iter t: QK(t+1) | SM(t) | PV(t) | DSW(t+2) | barrier | GLOB(t+3)
// Hazards: tile tau (buf tau%3) last read by PV(tau), next written by
// DSW(tau+3) one barrier later -> single barrier is sufficient.
// GLOB post-barrier drains only at the NEXT barrier (full-iter window).
// P in-register via permlane32_swap.  Defer-max THR=8.  Split-K S-way.
// ---------------------------------------------------------------------------
template<int S>
__global__ __launch_bounds__(256) void attn_kernel(
    const bf16_t* __restrict__ Q, const bf16_t* __restrict__ Kr,
    const bf16_t* __restrict__ Vt, bf16_t* __restrict__ Op, float* __restrict__ ml)
{
    __shared__ __align__(16) char kt[3][8192];
    __shared__ __align__(16) char vt[3][8192];

    const int tid  = threadIdx.x;
    const int s    = blockIdx.x % S;
    const int rem  = blockIdx.x / S;
    const int b    = rem / 63;
    const int qb   = rem % 63;
    const int q0   = qb * 128;
    const int t0   = (125 * s) / S;
    const int t1   = (125 * (s + 1)) / S;
    const int w    = tid >> 6;
    const int lane = tid & 63;
    const int lo   = lane & 31;
    const int hi   = lane >> 5;

    const int q  = q0 + w * 32 + lo;
    const int qc = q < NV ? q : NV - 1;

    bf16x8 bqf[4];
    {
        const bf16_t* qrow = Q + ((size_t)b * NV + qc) * 64 + hi * 8;
        #pragma unroll
        for (int kk = 0; kk < 4; ++kk)
            bqf[kk] = *reinterpret_cast<const bf16x8*>(qrow + kk * 16);
    }

    const char* kp = (const char*)(Kr + (size_t)b * NV * 64);
    const char* vp = (const char*)(Vt + (size_t)b * 64 * NV);

    // fragment-linear staging: wave w owns groups {w, w+4}.
    const int gk0 = w, gk1 = w + 4;
    const size_t koff0 = (size_t)((gk0 >> 2) * 32 + lo) * 128 + (gk0 & 3) * 32 + hi * 16;
    const size_t koff1 = (size_t)((gk1 >> 2) * 32 + lo) * 128 + (gk1 & 3) * 32 + hi * 16;
    const size_t voff0 = (size_t)((gk0 & 1) * 32 + lo) * (NV * 2) + (size_t)((gk0 >> 1) * 16 + hi * 8) * 2;
    const size_t voff1 = (size_t)((gk1 & 1) * 32 + lo) * (NV * 2) + (size_t)((gk1 >> 1) * 16 + hi * 8) * 2;
    const int dst0 = gk0 * 1024 + lane * 16;
    const int dst1 = gk1 * 1024 + lane * 16;

    uint4 rk0_, rk1_, rv0_, rv1_;
#define ATTN_GLOB(m0) do { \
    rk0_ = *reinterpret_cast<const uint4*>(kp + (size_t)(m0) * 128 + koff0); \
    rk1_ = *reinterpret_cast<const uint4*>(kp + (size_t)(m0) * 128 + koff1); \
    rv0_ = *reinterpret_cast<const uint4*>(vp + (size_t)(m0) * 2 + voff0); \
    rv1_ = *reinterpret_cast<const uint4*>(vp + (size_t)(m0) * 2 + voff1); } while (0)
#define ATTN_DSW(bufi) do { \
    *reinterpret_cast<uint4*>(kt[bufi] + dst0) = rk0_; \
    *reinterpret_cast<uint4*>(kt[bufi] + dst1) = rk1_; \
    *reinterpret_cast<uint4*>(vt[bufi] + dst0) = rv0_; \
    *reinterpret_cast<uint4*>(vt[bufi] + dst1) = rv1_; } while (0)
#define ATTN_QK(bufi, dst) do { \
    const char* ktb_ = kt[bufi]; \
    _Pragma("unroll") \
    for (int kb = 0; kb < 2; ++kb) { \
        f32x16 acc_{}; \
        _Pragma("unroll") \
        for (int kk = 0; kk < 4; ++kk) { \
            const bf16x8 ka_ = *reinterpret_cast<const bf16x8*>( \
                ktb_ + ((kb * 4 + kk) * 64 + lane) * 16); \
            acc_ = __builtin_amdgcn_mfma_f32_32x32x16_bf16(ka_, bqf[kk], acc_, 0, 0, 0); \
        } \
        dst[kb] = acc_; } } while (0)

    f32x16 acco[2]; acco[0] = f32x16{}; acco[1] = f32x16{};
    float m = -1e30f, l = 0.f;

    const int nt = t1 - t0;
    // prologue: LDS tiles t0, t0+1; regs hold tile t0+2
    ATTN_GLOB(t0 * 64); ATTN_DSW(0);
    if (nt > 1) { ATTN_GLOB((t0 + 1) * 64); ATTN_DSW(1); }
    if (nt > 2) ATTN_GLOB((t0 + 2) * 64);
    __syncthreads();

    f32x16 sa[2], sa2[2];
    ATTN_QK(0, sa);

    int p = 0;
    for (int t = t0; t < t1; ++t) {
        const int pn  = (p == 2) ? 0 : p + 1;
        const int pn2 = (pn == 2) ? 0 : pn + 1;

        if (t + 1 < t1) ATTN_QK(pn, sa2);   // mfma pipe; latency hides under SM(t)

        // ---- softmax(t): max tree + cross-half permlane ----
        float mx;
        {
            float v8[8];
            #pragma unroll
            for (int r = 0; r < 8; ++r)
                v8[r] = fmaxf(fmaxf(sa[0][r], sa[0][r + 8]),
                              fmaxf(sa[1][r], sa[1][r + 8]));
            float v4a = fmaxf(v8[0], v8[4]), v4b = fmaxf(v8[1], v8[5]);
            float v4c = fmaxf(v8[2], v8[6]), v4d = fmaxf(v8[3], v8[7]);
            mx = fmaxf(fmaxf(v4a, v4b), fmaxf(v4c, v4d));
        }
        {
            union { float f; unsigned u; } xu; xu.f = mx;
            uint2v r = __builtin_amdgcn_permlane32_swap(xu.u, xu.u, false, false);
            union { unsigned u; float f; } po; po.u = hi ? r[0] : r[1];
            mx = fmaxf(mx, po.f);
        }
        if (__any(mx > m + 8.0f)) {
            const float mn2 = fmaxf(m, mx);
            const float corr = EXP2(m - mn2);
            m = mn2;
            l *= corr;
            acco[0] *= corr;
            acco[1] *= corr;
        }

        float ps = 0.f;
        unsigned Uw[2][4][2];
        #pragma unroll
        for (int kb = 0; kb < 2; ++kb) {
            #pragma unroll
            for (int j = 0; j < 4; ++j) {
                float p0 = EXP2(sa[kb][4 * j + 0] - m);
                float p1 = EXP2(sa[kb][4 * j + 1] - m);
                float p2 = EXP2(sa[kb][4 * j + 2] - m);
                float p3 = EXP2(sa[kb][4 * j + 3] - m);
                ps += (p0 + p1) + (p2 + p3);
                Uw[kb][j][0] = pack2(p0, p1);
                Uw[kb][j][1] = pack2(p2, p3);
            }
        }
        {
            union { float f; unsigned u; } xu; xu.f = ps;
            uint2v r = __builtin_amdgcn_permlane32_swap(xu.u, xu.u, false, false);
            union { unsigned u; float f; } po; po.u = hi ? r[0] : r[1];
            ps += po.f;
        }
        l += ps;

        // ---- PV(t): P fragments via permlane32_swap; V from vt[p] ----
        const char* vtb = vt[p];
        #pragma unroll
        for (int kb = 0; kb < 2; ++kb) {
            #pragma unroll
            for (int e = 0; e < 2; ++e) {
                uint2v r0 = __builtin_amdgcn_permlane32_swap(
                    Uw[kb][2 * e][0], Uw[kb][2 * e + 1][0], false, false);
                uint2v r1 = __builtin_amdgcn_permlane32_swap(
                    Uw[kb][2 * e][1], Uw[kb][2 * e + 1][1], false, false);
                union { unsigned u[4]; bf16x8 v; } pf;
                pf.u[0] = r0[0]; pf.u[1] = r1[0];
                pf.u[2] = r0[1]; pf.u[3] = r1[1];
                const int ks = kb * 2 + e;
                #pragma unroll
                for (int vb = 0; vb < 2; ++vb) {
                    const bf16x8 va = *reinterpret_cast<const bf16x8*>(
                        vtb + ((ks * 2 + vb) * 64 + lane) * 16);
                    acco[vb] = __builtin_amdgcn_mfma_f32_32x32x16_bf16(va, pf.v, acco[vb], 0, 0, 0);
                }
            }
        }

        if (t + 2 < t1) ATTN_DSW(pn2);            // write tile t+2 (pre-barrier; safe: last
                                                  // reader PV(t-1) was before prev barrier)
        __syncthreads();                          // single barrier per tile
        if (t + 3 < t1) ATTN_GLOB((t + 3) * 64);  // drains only at NEXT barrier
        if (t + 1 < t1) { sa[0] = sa2[0]; sa[1] = sa2[1]; }
        p = pn;
    }

    // epilogue: lane owns query q; acco[vb][4j+i] = O[q][32vb + 8j + 4hi + i]
    if (q < NV) {
        const size_t obase = ((size_t)(s * 2 + b) * NV + q) * 64;
        #pragma unroll
        for (int vb = 0; vb < 2; ++vb) {
            #pragma unroll
            for (int j = 0; j < 4; ++j) {
                union { uint2 u2; bf16_t h[4]; } pk;
                #pragma unroll
                for (int i = 0; i < 4; ++i) pk.h[i] = (bf16_t)acco[vb][4 * j + i];
                *reinterpret_cast<uint2*>(&Op[obase + vb * 32 + 8 * j + 4 * hi]) = pk.u2;
            }
        }
        if (hi == 0) {
            float2 t2; t2.x = m; t2.y = l;
            *reinterpret_cast<float2*>(&ml[((size_t)(s * 2 + b) * NV + q) * 2]) = t2;
        }
    }
#undef ATTN_GLOB
#undef ATTN_DSW
#undef ATTN_QK
}

// ---------------------------------------------------------------------------
// Kernel 3: fused split-K combine + output projection, nf-split 4-way.
// (unchanged, R8; Op is bf16)
// ---------------------------------------------------------------------------
template<int S>
__global__ __launch_bounds__(256) void projc_kernel(
    const bf16_t* __restrict__ Op, const float* __restrict__ ml,
    const float* __restrict__ wo, const float* __restrict__ bo,
    float* __restrict__ out)
{
    __shared__ __align__(16) char bt[16 * 128];
    __shared__ float al[64 * 8];

    const int tid = threadIdx.x;
    const int b   = blockIdx.x / 500;
    const int rem = blockIdx.x % 500;
    const int a   = rem >> 2;
    const int nf  = rem & 3;

    if (tid < 64) {
        const int row = a * 64 + tid;
        float M = -1e30f;
        #pragma unroll
        for (int s = 0; s < S; ++s)
            M = fmaxf(M, ml[((size_t)(s * 2 + b) * NV + row) * 2]);
        float L = 0.f, av[S];
        #pragma unroll
        for (int s = 0; s < S; ++s) {
            const float mm = ml[((size_t)(s * 2 + b) * NV + row) * 2];
            const float ll = ml[((size_t)(s * 2 + b) * NV + row) * 2 + 1];
            const float aa = EXP2(mm - M);
            L += ll * aa;
            av[s] = aa;
        }
        const float inv = 1.0f / L;
        #pragma unroll
        for (int s = 0; s < S; ++s) al[tid * 8 + s] = av[s] * inv;
    }
    __syncthreads();

    {
        const int c = tid >> 2, sg = tid & 3;
        f32x4 acc = {0.f, 0.f, 0.f, 0.f};
        #pragma unroll
        for (int s = 0; s < S; ++s) {
            const float fac = al[c * 8 + s];
            union { uint2 u2; bf16_t h[4]; } cv;
            cv.u2 = *reinterpret_cast<const uint2*>(
                &Op[((size_t)(s * 2 + b) * NV + a * 64 + c) * 64 + nf * 16 + sg * 4]);
            #pragma unroll
            for (int jj = 0; jj < 4; ++jj) acc[jj] += fac * (float)cv.h[jj];
        }
        #pragma unroll
        for (int jj = 0; jj < 4; ++jj) {
            const int v = sg * 4 + jj;
            *reinterpret_cast<bf16_t*>(bt + v * 128 + ((c * 2) ^ ((v & 7) << 4))) =
                (bf16_t)acc[jj];
        }
    }
    __syncthreads();

    const int w  = tid >> 6;
    const int lane = tid & 63;
    const int g  = lane >> 4;
    const int lr = lane & 15;

    const int orow = w * 16 + lr;
    const bf16x8 wa0 = cvt_bf16x8(wo + orow * 64 + 8 * g);
    const bf16x8 wa1 = cvt_bf16x8(wo + orow * 64 + 32 + 8 * g);
    const float4 bo4 = *reinterpret_cast<const float4*>(&bo[w * 16 + 4 * g]);

    const f32x4 zero4 = {0.f, 0.f, 0.f, 0.f};
    const bf16x8 gb0 = *reinterpret_cast<const bf16x8*>(
        bt + lr * 128 + ((16 * g) ^ ((lr & 7) << 4)));
    const bf16x8 gb1 = *reinterpret_cast<const bf16x8*>(
        bt + lr * 128 + ((64 + 16 * g) ^ ((lr & 7) << 4)));
    f32x4 acc = __builtin_amdgcn_mfma_f32_16x16x32_bf16(wa0, gb0, zero4, 0, 0, 0);
    acc = __builtin_amdgcn_mfma_f32_16x16x32_bf16(wa1, gb1, acc, 0, 0, 0);
    #pragma unroll
    for (int jj = 0; jj < 4; ++jj) {
        const int o = w * 16 + 4 * g + jj;
        out[((size_t)b * 64 + o) * NV + a * 64 + nf * 16 + lr] = acc[jj] + (&bo4.x)[jj];
    }
}

// ---------------------------------------------------------------------------
extern "C" void kernel_launch(void* const* d_in, const int* in_sizes, int n_in,
                              void* d_out, int out_size, void* d_ws, size_t ws_size,
                              hipStream_t stream)
{
    const float* x  = (const float*)d_in[0];
    const float* wq = (const float*)d_in[1];
    const float* bq = (const float*)d_in[2];
    const float* wk = (const float*)d_in[3];
    const float* bk = (const float*)d_in[4];
    const float* wv = (const float*)d_in[5];
    const float* bv = (const float*)d_in[6];
    const float* wo = (const float*)d_in[7];
    const float* bo = (const float*)d_in[8];
    float* out = (float*)d_out;

    // ws: Q(2,048,000) | K(2,048,000) | Vt(2,048,000) | Op bf16 (S*2,048,000) | ml (S*128,000)
    char* ws = (char*)d_ws;
    bf16_t* Q  = (bf16_t*)(ws);
    bf16_t* Kr = (bf16_t*)(ws + 2048000);
    bf16_t* Vt = (bf16_t*)(ws + 4096000);

    int S = 8;
    if (ws_size < 6144000ull + 8ull * 2176000ull) S = 4;
    if (ws_size < 6144000ull + 4ull * 2176000ull) S = 2;
    if (ws_size < 6144000ull + 2ull * 2176000ull) S = 1;

    bf16_t* Op = (bf16_t*)(ws + 6144000);
    float*  ml = (float*)(ws + 6144000 + (size_t)S * 2048000);

    qkv_kernel<<<dim3(2 * 500), dim3(256), 0, stream>>>(x, wq, bq, wk, bk, wv, bv, Q, Kr, Vt);

    if (S == 8) {
        attn_kernel<8><<<dim3(8 * 2 * 63), dim3(256), 0, stream>>>(Q, Kr, Vt, Op, ml);
        projc_kernel<8><<<dim3(2 * 500), dim3(256), 0, stream>>>(Op, ml, wo, bo, out);
    } else if (S == 4) {
        attn_kernel<4><<<dim3(4 * 2 * 63), dim3(256), 0, stream>>>(Q, Kr, Vt, Op, ml);
        projc_kernel<4><<<dim3(2 * 500), dim3(256), 0, stream>>>(Op, ml, wo, bo, out);
    } else if (S == 2) {
        attn_kernel<2><<<dim3(2 * 2 * 63), dim3(256), 0, stream>>>(Q, Kr, Vt, Op, ml);
        projc_kernel<2><<<dim3(2 * 500), dim3(256), 0, stream>>>(Op, ml, wo, bo, out);
    } else {
        attn_kernel<1><<<dim3(1 * 2 * 63), dim3(256), 0, stream>>>(Q, Kr, Vt, Op, ml);
        projc_kernel<1><<<dim3(2 * 500), dim3(256), 0, stream>>>(Op, ml, wo, bo, out);
    }
}